// Round 14
// baseline (188.914 us; speedup 1.0000x reference)
//
#include <hip/hip_runtime.h>
#include <stdint.h>

#define HIDDEN 1536
#define NHEAD 12
#define HD 128
#define TSEQ 2048
#define NROWS 4096
#define KDIM HIDDEN
#define EPS_F 1.1920928955078125e-07f
// (1/sqrt(128)) * log2(e)
#define SCALE_LOG2E 0.12751879110195655f
// fixed softmax shift (log2 domain): scores bounded by sqrt(128)=11.314 (RMS-normed
// q,k => |q||k|<=128 by Cauchy-Schwarz), *log2(e) = 16.32; use 16.6 for bf16 margin.
#define FIXSUB 16.6f

typedef unsigned short u16;
typedef __bf16 bf16x8_t __attribute__((ext_vector_type(8)));
typedef float f32x4_t __attribute__((ext_vector_type(4)));

#define MFMA16(a, b, c) __builtin_amdgcn_mfma_f32_16x16x32_bf16((a), (b), (c), 0, 0, 0)
#define GLL(srcp, dstp) \
  __builtin_amdgcn_global_load_lds((const __attribute__((address_space(1))) void*)(srcp), \
                                   (__attribute__((address_space(3))) void*)(dstp), 16, 0, 0)

__device__ __forceinline__ u16 f2bf(float f) {
  unsigned u = __builtin_bit_cast(unsigned, f);
  u = (u + 0x7fffu + ((u >> 16) & 1u)) >> 16;
  return (u16)u;
}
__device__ __forceinline__ float bfu(u16 v) {
  return __builtin_bit_cast(float, ((unsigned)v) << 16);
}

// ---------------- cast fp32 -> bf16 (vectorized) ----------------
__global__ __launch_bounds__(256) void cast_kernel(const float* __restrict__ in,
                                                   u16* __restrict__ out, int n) {
  int i = (blockIdx.x * 256 + threadIdx.x) * 4;
  if (i >= n) return;
  float4 v = *reinterpret_cast<const float4*>(in + i);
  uint2 pk;
  pk.x = (unsigned)f2bf(v.x) | ((unsigned)f2bf(v.y) << 16);
  pk.y = (unsigned)f2bf(v.z) | ((unsigned)f2bf(v.w) << 16);
  *reinterpret_cast<uint2*>(out + i) = pk;
}

// 4 equal-size weight casts in one launch (blockIdx.y selects)
__global__ __launch_bounds__(256) void cast4_kernel(
    const float* __restrict__ a, const float* __restrict__ b, const float* __restrict__ c,
    const float* __restrict__ d, u16* __restrict__ oa, u16* __restrict__ ob,
    u16* __restrict__ oc, u16* __restrict__ od, int n) {
  const float* in;
  u16* out;
  switch (blockIdx.y) {
    case 0: in = a; out = oa; break;
    case 1: in = b; out = ob; break;
    case 2: in = c; out = oc; break;
    default: in = d; out = od; break;
  }
  int i = (blockIdx.x * 256 + threadIdx.x) * 4;
  if (i >= n) return;
  float4 v = *reinterpret_cast<const float4*>(in + i);
  uint2 pk;
  pk.x = (unsigned)f2bf(v.x) | ((unsigned)f2bf(v.y) << 16);
  pk.y = (unsigned)f2bf(v.z) | ((unsigned)f2bf(v.w) << 16);
  *reinterpret_cast<uint2*>(out + i) = pk;
}

// ---------------- shared NT-GEMM mainloop, BK=64, single-barrier 2-phase ----------------
// 128x128 tile, 4 waves, double-buffered 64KB LDS, 2 blocks/CU.
// T3 minimum-2-phase schedule (guide-verified): STAGE(next) | ds_read+MFMA |
// lgkm(0) | vmcnt(0) | barrier. ONE barrier per K-tile (was 2 in R8/R13);
// bottom-placed drain gives this iter's loads the whole ds_read+MFMA phase of
// cover (loads are L2-hot per FETCH evidence). Hazards: writes to buf[cur^1]
// ordered after prior-iter reads by the prior barrier (lgkm(0) precedes it);
// reads of buf[cur] ordered after its loads by prior iter's vmcnt(0)+barrier.
// XOR-swizzled LDS via pre-swizzled global source + matching XOR on ds_read.
__device__ __forceinline__ void gemm_mainloop64(const u16* __restrict__ A,
                                                const u16* __restrict__ W, int M0, int N0,
                                                u16* lds, f32x4_t acc[4][4], int tid) {
  const int w = tid >> 6, l = tid & 63;
  const int lrow = l & 15, kg = l >> 4;
  const int wr = (w >> 1) * 64, wc = (w & 1) * 64;
  const int row0 = tid >> 3, j0 = tid & 7;
  const unsigned jsw = (unsigned)((j0 ^ (row0 & 7)) * 8);
  unsigned offA = (unsigned)((M0 + row0) * KDIM) + jsw;
  unsigned offW = (unsigned)((N0 + row0) * KDIM) + jsw;
  const u16* A1 = A + 32 * KDIM; const u16* A2 = A + 64 * KDIM; const u16* A3 = A + 96 * KDIM;
  const u16* W1 = W + 32 * KDIM; const u16* W2 = W + 64 * KDIM; const u16* W3 = W + 96 * KDIM;
  auto issue = [&](int buf) {
    u16* da = lds + buf * 8192 + w * 512;
    u16* dw = lds + 16384 + buf * 8192 + w * 512;
    GLL(A + offA, da);          GLL(A1 + offA, da + 2048);
    GLL(A2 + offA, da + 4096);  GLL(A3 + offA, da + 6144);
    GLL(W + offW, dw);          GLL(W1 + offW, dw + 2048);
    GLL(W2 + offW, dw + 4096);  GLL(W3 + offW, dw + 6144);
    offA += 64; offW += 64;
  };
  // prologue: buf0 staged and visible
  issue(0);
  asm volatile("s_waitcnt vmcnt(0)" ::: "memory");
  __builtin_amdgcn_s_barrier();
  asm volatile("" ::: "memory");
  const int NT = KDIM / 64;  // 24
#pragma unroll 1
  for (int kt = 0; kt < NT; ++kt) {
    const int cur = kt & 1;
    if (kt + 1 < NT) issue(cur ^ 1);  // stage next tile into other buffer
    const u16* Ab = lds + cur * 8192;
    const u16* Wb = lds + 16384 + cur * 8192;
#pragma unroll
    for (int s = 0; s < 2; ++s) {
      bf16x8_t af[4], bf_[4];
#pragma unroll
      for (int mi = 0; mi < 4; ++mi) {
        const int row = wr + mi * 16 + lrow;
        af[mi] = *reinterpret_cast<const bf16x8_t*>(Ab + row * 64 +
                                                    (((s << 2) | kg) ^ (row & 7)) * 8);
      }
#pragma unroll
      for (int ni = 0; ni < 4; ++ni) {
        const int row = wc + ni * 16 + lrow;
        bf_[ni] = *reinterpret_cast<const bf16x8_t*>(Wb + row * 64 +
                                                     (((s << 2) | kg) ^ (row & 7)) * 8);
      }
#pragma unroll
      for (int mi = 0; mi < 4; ++mi)
#pragma unroll
        for (int ni = 0; ni < 4; ++ni)
          acc[mi][ni] = MFMA16(af[mi], bf_[ni], acc[mi][ni]);
    }
    asm volatile("s_waitcnt lgkmcnt(0)" ::: "memory");  // all buf[cur] reads in regs
    asm volatile("s_waitcnt vmcnt(0)" ::: "memory");    // next tile's loads landed
    __builtin_amdgcn_s_barrier();
    asm volatile("" ::: "memory");
  }
}

// ---------------- QKV projection + fused RoPE/RMSNorm epilogue (per-z blocks) ----------------
// Grid 1152 flattened, XCD-chunked (8 XCDs x [8m x 18nz]); A-band L2-resident.
// Epilogue: stage C bf16 swizzled into first 16KB of LDS, then
// z=0/1: in-block RoPE+RMSNorm -> qh/kh; z=2: transpose -> vt, 16B stores.
__global__ __launch_bounds__(256) void gemm_qkv_kernel(
    const u16* __restrict__ xb, const u16* __restrict__ wq, const u16* __restrict__ wk,
    const u16* __restrict__ wv, const float* __restrict__ cosp, const float* __restrict__ sinp,
    u16* __restrict__ qh, u16* __restrict__ kh, u16* __restrict__ vt) {
  __shared__ __align__(16) u16 lds[32768];
  const int tid = threadIdx.x;
  const int wgid = blockIdx.x;
  const int xcd = wgid & 7, c = wgid >> 3;      // c in [0,144)
  const int m = ((xcd & 3) << 3) + (c & 7);     // 0..31
  const int nz = ((xcd >> 2) * 18) + (c >> 3);  // 0..35
  const int z = nz / 12, n = nz % 12;
  const int M0 = m * 128, N0 = n * 128;
  const u16* W = (z == 0) ? wq : (z == 1) ? wk : wv;
  f32x4_t acc[4][4] = {};
  gemm_mainloop64(xb, W, M0, N0, lds, acc, tid);
  const int w = tid >> 6, l = tid & 63;
  const int lrow = l & 15, kg = l >> 4;
  const int wr = (w >> 1) * 64, wc = (w & 1) * 64;
  char* cs = reinterpret_cast<char*>(lds);
  if (z == 2) {
#pragma unroll
    for (int mi = 0; mi < 4; ++mi)
#pragma unroll
      for (int ni = 0; ni < 4; ++ni)
#pragma unroll
        for (int r = 0; r < 4; ++r) {
          const int t_l = wr + mi * 16 + kg * 4 + r;
          const int d = wc + ni * 16 + lrow;
          const int bofs = (d * 256 + t_l * 2) ^ ((d & 7) << 4);
          *reinterpret_cast<u16*>(cs + bofs) = f2bf(acc[mi][ni][r]);
        }
  } else {
#pragma unroll
    for (int mi = 0; mi < 4; ++mi)
#pragma unroll
      for (int ni = 0; ni < 4; ++ni)
#pragma unroll
        for (int r = 0; r < 4; ++r) {
          const int t_l = wr + mi * 16 + kg * 4 + r;
          const int d = wc + ni * 16 + lrow;
          const int bofs = (t_l * 256 + d * 2) ^ ((t_l & 7) << 4);
          *reinterpret_cast<u16*>(cs + bofs) = f2bf(acc[mi][ni][r]);
        }
  }
  __syncthreads();
  const int rr = tid >> 1, hh = tid & 1;
  const int bb = M0 >> 11;
  const int t0 = M0 & (TSEQ - 1);
  const size_t bhn = (size_t)(bb * NHEAD + n);
  if (z == 2) {
    u16* dst = vt + (bhn * HD + rr) * TSEQ + t0 + hh * 64;
    const char* base = cs + rr * 256 + hh * 128;
#pragma unroll
    for (int j = 0; j < 8; ++j) {
      uint4 v = *reinterpret_cast<const uint4*>(base + ((j ^ (rr & 7)) * 16));
      *reinterpret_cast<uint4*>(dst + j * 8) = v;
    }
  } else {
    const int t = t0 + rr;
    const float* cosb = cosp + t * 64;
    const float* sinb = sinp + t * 64;
    const char* base = cs + rr * 256;
    float ss = 0.0f;
    unsigned pk[32];
#pragma unroll
    for (int j = 0; j < 8; ++j) {
      const int jp = (j ^ (rr & 7)) * 16;
      uint4 vo = *reinterpret_cast<const uint4*>(base + hh * 128 + jp);
      uint4 vx = *reinterpret_cast<const uint4*>(base + (hh ^ 1) * 128 + jp);
      const unsigned vo32[4] = {vo.x, vo.y, vo.z, vo.w};
      const unsigned vx32[4] = {vx.x, vx.y, vx.z, vx.w};
      const float* cj = cosb + j * 8;
      const float* sj = sinb + j * 8;
#pragma unroll
      for (int q2 = 0; q2 < 4; ++q2) {
        float o0 = bfu((u16)(vo32[q2] & 0xffffu)), o1 = bfu((u16)(vo32[q2] >> 16));
        float x0 = bfu((u16)(vx32[q2] & 0xffffu)), x1 = bfu((u16)(vx32[q2] >> 16));
        float cc0 = cj[q2 * 2], cc1 = cj[q2 * 2 + 1];
        float s0 = sj[q2 * 2], s1 = sj[q2 * 2 + 1];
        float y0 = hh ? __builtin_fmaf(o0, cc0, -x0 * s0) : __builtin_fmaf(o0, cc0, x0 * s0);
        float y1 = hh ? __builtin_fmaf(o1, cc1, -x1 * s1) : __builtin_fmaf(o1, cc1, x1 * s1);
        ss = __builtin_fmaf(y0, y0, __builtin_fmaf(y1, y1, ss));
        pk[j * 4 + q2] = (unsigned)f2bf(y0) | ((unsigned)f2bf(y1) << 16);
      }
    }
    ss += __shfl_xor(ss, 1, 64);
    const float rinv = rsqrtf(ss * (1.0f / 128.0f) + EPS_F);
    u16* dst = ((z == 0) ? qh : kh) + (bhn * TSEQ + t) * HD + hh * 64;
#pragma unroll
    for (int j = 0; j < 8; ++j) {
      unsigned o[4];
#pragma unroll
      for (int q2 = 0; q2 < 4; ++q2) {
        float y0 = bfu((u16)(pk[j * 4 + q2] & 0xffffu)) * rinv;
        float y1 = bfu((u16)(pk[j * 4 + q2] >> 16)) * rinv;
        o[q2] = (unsigned)f2bf(y0) | ((unsigned)f2bf(y1) << 16);
      }
      uint4 v;
      v.x = o[0]; v.y = o[1]; v.z = o[2]; v.w = o[3];
      *reinterpret_cast<uint4*>(dst + j * 8) = v;
    }
  }
}

// ---------------- output projection (flattened grid, XCD-chunked) ----------------
__global__ __launch_bounds__(256) void gemm_out_kernel(const u16* __restrict__ yh,
                                                       const u16* __restrict__ wp,
                                                       float* __restrict__ out) {
  __shared__ __align__(16) u16 lds[32768];
  const int tid = threadIdx.x;
  const int wgid = blockIdx.x;
  const int xcd = wgid & 7, c = wgid >> 3;
  const int m = ((xcd & 3) << 3) + (c & 7);
  const int n = ((xcd >> 2) * 6) + (c >> 3);
  const int M0 = m * 128, N0 = n * 128;
  f32x4_t acc[4][4] = {};
  gemm_mainloop64(yh, wp, M0, N0, lds, acc, tid);
  const int w = tid >> 6, l = tid & 63;
  const int lrow = l & 15, kg = l >> 4;
  const int wr = (w >> 1) * 64, wc = (w & 1) * 64;
#pragma unroll
  for (int mi = 0; mi < 4; ++mi)
#pragma unroll
    for (int ni = 0; ni < 4; ++ni)
#pragma unroll
      for (int r = 0; r < 4; ++r) {
        const int grow = M0 + wr + mi * 16 + kg * 4 + r;
        const int gcol = N0 + wc + ni * 16 + lrow;
        out[(size_t)grow * HIDDEN + gcol] = acc[mi][ni][r];
      }
}

// ---------------- flash attention: 2-barrier pipeline, dbuf K AND V (R9-proven) ----------------
__global__ __launch_bounds__(512, 4) void attn_kernel(const u16* __restrict__ qh,
                                                      const u16* __restrict__ kh,
                                                      const u16* __restrict__ vt,
                                                      u16* __restrict__ yh,
                                                      const int* __restrict__ winp) {
  __shared__ __align__(16) u16 Kl[2][8192];  // [buf][64 keys x 128 d], swizzled
  __shared__ __align__(16) u16 Vl[2][8192];  // [buf][128 d x 64 t], swizzled
  __shared__ __align__(16) u16 Pl[8][1024];  // per-wave 16x64 P, swizzled
  const int tid = threadIdx.x, w = tid >> 6, l = tid & 63;
  const int lrow = l & 15, kg = l >> 4;
  const int bid = blockIdx.x;  // 384 = 8 XCDs x 48
  const int swz = (bid & 7) * 48 + (bid >> 3);
  const int qb = swz & 15;  // q-block (128 rows) within (b,h)
  const int bh = swz >> 4;  // 0..23
  const int h = bh % NHEAD, b = bh / NHEAD;
  const int win = winp[0];
  const u16* Q = qh + (size_t)bh * TSEQ * HD;
  const u16* K = kh + (size_t)bh * TSEQ * HD;
  const u16* V = vt + (size_t)bh * HD * TSEQ;
  const int qw = qb * 128 + w * 16;  // this wave's 16 q-rows
  bf16x8_t aq[4];
#pragma unroll
  for (int ks = 0; ks < 4; ++ks)
    aq[ks] = *reinterpret_cast<const bf16x8_t*>(Q + (qw + lrow) * HD + ks * 32 + kg * 8);
  float lsum[4] = {0.f, 0.f, 0.f, 0.f};  // per-lane partial row sums (reduced post-loop)
  f32x4_t accv[8] = {};
  int lo = qb * 128 - win;
  if (lo < 0) lo = 0;
  lo &= ~63;
  const int last = qb * 128 + 64;  // last KV tile start (diagonal tile)

  u16* Pw = &Pl[w][0];

  auto stage_k = [&](int kv, int buf) {
#pragma unroll
    for (int i = 0; i < 2; ++i) {
      const int c = i * 512 + w * 64 + l;
      const int row = c >> 4, j = c & 15;
      const u16* src = K + (size_t)(kv + row) * HD + ((j ^ (row & 7)) * 8);
      GLL(src, &Kl[buf][0] + i * 4096 + w * 512);
    }
  };
  auto stage_v = [&](int kv, int buf) {
#pragma unroll
    for (int i = 0; i < 2; ++i) {
      const int c = i * 512 + w * 64 + l;
      const int row = c >> 3, j = c & 7;
      const u16* src = V + (size_t)row * TSEQ + kv + ((j ^ (row & 7)) * 8);
      GLL(src, &Vl[buf][0] + i * 4096 + w * 512);
    }
  };

  stage_k(lo, 0);
  stage_v(lo, 0);  // prologue: 4 loads in flight
  int it = 0;
  for (int kv = lo; kv <= last; kv += 64, ++it) {
    const int cur = it & 1;
    const int kpre = (kv + 64 <= last) ? kv + 64 : last;  // clamp tail prefetch
    stage_k(kpre, cur ^ 1);                               // +2 -> 6 outstanding
    asm volatile("s_waitcnt vmcnt(2)" ::: "memory");      // K(kv),V(kv) landed
    __builtin_amdgcn_s_barrier();                         // b1
    asm volatile("" ::: "memory");
    stage_v(kpre, cur ^ 1);  // +2 (Vl[cur^1] PV-reads all finished before b1)
    // ---- S = Q K^T (16 x 64) from LDS ----
    const u16* Kb = &Kl[cur][0];
    f32x4_t s[4] = {};
#pragma unroll
    for (int n = 0; n < 4; ++n) {
      const int row = n * 16 + lrow;
#pragma unroll
      for (int ks = 0; ks < 4; ++ks) {
        bf16x8_t bk = *reinterpret_cast<const bf16x8_t*>(
            Kb + row * 128 + (((ks << 2) | kg) ^ (row & 7)) * 8);
        s[n] = MFMA16(aq[ks], bk, s[n]);
      }
    }
    // ---- softmax: interior tiles need no mask (wave-uniform test) ----
    float ps[4][4];
    const bool interior = (kv + 63 <= qw) && ((qw + 15) - kv <= win);
    if (interior) {
#pragma unroll
      for (int n = 0; n < 4; ++n)
#pragma unroll
        for (int r = 0; r < 4; ++r)
          ps[n][r] = exp2f(__builtin_fmaf(s[n][r], SCALE_LOG2E, -FIXSUB));
    } else {
#pragma unroll
      for (int n = 0; n < 4; ++n) {
        const int key = kv + n * 16 + lrow;
#pragma unroll
        for (int r = 0; r < 4; ++r) {
          const int rowq = qw + kg * 4 + r;
          const bool ok = (key <= rowq) && (rowq - key <= win);
          ps[n][r] = ok ? exp2f(__builtin_fmaf(s[n][r], SCALE_LOG2E, -FIXSUB)) : 0.0f;
        }
      }
    }
#pragma unroll
    for (int r = 0; r < 4; ++r)
      lsum[r] += (ps[0][r] + ps[1][r]) + (ps[2][r] + ps[3][r]);
    // ---- P (bf16) -> swizzled per-wave LDS: D-frag -> A-frag layout ----
#pragma unroll
    for (int n = 0; n < 4; ++n)
#pragma unroll
      for (int r = 0; r < 4; ++r) {
        const int rp = kg * 4 + r;
        int bofs = rp * 128 + (n * 16 + lrow) * 2;
        bofs ^= (rp & 7) << 4;
        *reinterpret_cast<u16*>(reinterpret_cast<char*>(Pw) + bofs) = f2bf(ps[n][r]);
      }
    asm volatile("s_waitcnt lgkmcnt(0)" ::: "memory");
    __builtin_amdgcn_s_barrier();  // b2: QK reads of Kl[cur] done before next issueK
    asm volatile("" ::: "memory");
    // ---- O += P V ----
    bf16x8_t ap[2];
#pragma unroll
    for (int k2 = 0; k2 < 2; ++k2) {
      int bofs = lrow * 128 + k2 * 64 + kg * 16;
      bofs ^= (lrow & 7) << 4;
      ap[k2] = *reinterpret_cast<const bf16x8_t*>(reinterpret_cast<const char*>(Pw) + bofs);
    }
    const u16* Vb = &Vl[cur][0];
#pragma unroll
    for (int k2 = 0; k2 < 2; ++k2)
#pragma unroll
      for (int dn = 0; dn < 8; ++dn) {
        const int row = dn * 16 + lrow;
        bf16x8_t bv = *reinterpret_cast<const bf16x8_t*>(
            Vb + row * 64 + (((k2 << 2) | kg) ^ (row & 7)) * 8);
        accv[dn] = MFMA16(ap[k2], bv, accv[dn]);
      }
  }
  // ---- deferred row-sum reduce (within each 16-lane lrow group) ----
#pragma unroll
  for (int off = 1; off < 16; off <<= 1)
#pragma unroll
    for (int r = 0; r < 4; ++r) lsum[r] += __shfl_xor(lsum[r], off, 64);
  float inv[4];
#pragma unroll
  for (int r = 0; r < 4; ++r) inv[r] = 1.0f / lsum[r];
#pragma unroll
  for (int dn = 0; dn < 8; ++dn)
#pragma unroll
    for (int r = 0; r < 4; ++r) {
      const int rowg = b * TSEQ + qw + kg * 4 + r;
      const int col = h * HD + dn * 16 + lrow;
      yh[(size_t)rowg * HIDDEN + col] = f2bf(accv[dn][r] * inv[r]);
    }
}

extern "C" void kernel_launch(void* const* d_in, const int* in_sizes, int n_in, void* d_out,
                              int out_size, void* d_ws, size_t ws_size, hipStream_t stream) {
  const float* x = (const float*)d_in[0];
  const float* cosp = (const float*)d_in[1];
  const float* sinp = (const float*)d_in[2];
  const float* Wq = (const float*)d_in[3];
  const float* Wk = (const float*)d_in[4];
  const float* Wv = (const float*)d_in[5];
  const float* Wp = (const float*)d_in[6];
  const int* winp = (const int*)d_in[7];

  char* ws = (char*)d_ws;
  size_t off = 0;
  auto alloc = [&](size_t bytes) {
    char* p = ws + off;
    off += (bytes + 255) & ~(size_t)255;
    return p;
  };
  u16* xb = (u16*)alloc((size_t)NROWS * HIDDEN * 2);
  u16* wqb = (u16*)alloc((size_t)HIDDEN * HIDDEN * 2);
  u16* wkb = (u16*)alloc((size_t)HIDDEN * HIDDEN * 2);
  u16* wvb = (u16*)alloc((size_t)HIDDEN * HIDDEN * 2);
  u16* wpb = (u16*)alloc((size_t)HIDDEN * HIDDEN * 2);
  u16* qh = (u16*)alloc((size_t)NROWS * HIDDEN * 2);
  u16* kh = (u16*)alloc((size_t)NROWS * HIDDEN * 2);
  u16* vt = (u16*)alloc((size_t)NROWS * HIDDEN * 2);
  u16* yh = (u16*)alloc((size_t)NROWS * HIDDEN * 2);

  const int nx = NROWS * HIDDEN;   // 6291456
  const int nw = HIDDEN * HIDDEN;  // 2359296
  cast_kernel<<<nx / 1024, 256, 0, stream>>>(x, xb, nx);
  cast4_kernel<<<dim3(nw / 1024, 4), 256, 0, stream>>>(Wq, Wk, Wv, Wp, wqb, wkb, wvb, wpb, nw);

  gemm_qkv_kernel<<<dim3(1152), 256, 0, stream>>>(xb, wqb, wkb, wvb, cosp, sinp, qh, kh, vt);
  attn_kernel<<<dim3(384), 512, 0, stream>>>(qh, kh, vt, yh, winp);
  gemm_out_kernel<<<dim3(384), 256, 0, stream>>>(yh, wpb, (float*)d_out);
}

// Round 15
// 185.916 us; speedup vs baseline: 1.0161x; 1.0161x over previous
//
#include <hip/hip_runtime.h>
#include <stdint.h>

#define HIDDEN 1536
#define NHEAD 12
#define HD 128
#define TSEQ 2048
#define NROWS 4096
#define KDIM HIDDEN
#define EPS_F 1.1920928955078125e-07f
// (1/sqrt(128)) * log2(e)
#define SCALE_LOG2E 0.12751879110195655f
// fixed softmax shift (log2 domain): scores bounded by sqrt(128)=11.314 (RMS-normed
// q,k => |q||k|<=128 by Cauchy-Schwarz), *log2(e) = 16.32; use 16.6 for bf16 margin.
#define FIXSUB 16.6f

typedef unsigned short u16;
typedef __bf16 bf16x8_t __attribute__((ext_vector_type(8)));
typedef float f32x4_t __attribute__((ext_vector_type(4)));

#define MFMA16(a, b, c) __builtin_amdgcn_mfma_f32_16x16x32_bf16((a), (b), (c), 0, 0, 0)
#define GLL(srcp, dstp) \
  __builtin_amdgcn_global_load_lds((const __attribute__((address_space(1))) void*)(srcp), \
                                   (__attribute__((address_space(3))) void*)(dstp), 16, 0, 0)

__device__ __forceinline__ u16 f2bf(float f) {
  unsigned u = __builtin_bit_cast(unsigned, f);
  u = (u + 0x7fffu + ((u >> 16) & 1u)) >> 16;
  return (u16)u;
}
__device__ __forceinline__ float bfu(u16 v) {
  return __builtin_bit_cast(float, ((unsigned)v) << 16);
}

// ---------------- cast fp32 -> bf16 (vectorized) ----------------
__global__ __launch_bounds__(256) void cast_kernel(const float* __restrict__ in,
                                                   u16* __restrict__ out, int n) {
  int i = (blockIdx.x * 256 + threadIdx.x) * 4;
  if (i >= n) return;
  float4 v = *reinterpret_cast<const float4*>(in + i);
  uint2 pk;
  pk.x = (unsigned)f2bf(v.x) | ((unsigned)f2bf(v.y) << 16);
  pk.y = (unsigned)f2bf(v.z) | ((unsigned)f2bf(v.w) << 16);
  *reinterpret_cast<uint2*>(out + i) = pk;
}

// 4 equal-size weight casts in one launch (blockIdx.y selects)
__global__ __launch_bounds__(256) void cast4_kernel(
    const float* __restrict__ a, const float* __restrict__ b, const float* __restrict__ c,
    const float* __restrict__ d, u16* __restrict__ oa, u16* __restrict__ ob,
    u16* __restrict__ oc, u16* __restrict__ od, int n) {
  const float* in;
  u16* out;
  switch (blockIdx.y) {
    case 0: in = a; out = oa; break;
    case 1: in = b; out = ob; break;
    case 2: in = c; out = oc; break;
    default: in = d; out = od; break;
  }
  int i = (blockIdx.x * 256 + threadIdx.x) * 4;
  if (i >= n) return;
  float4 v = *reinterpret_cast<const float4*>(in + i);
  uint2 pk;
  pk.x = (unsigned)f2bf(v.x) | ((unsigned)f2bf(v.y) << 16);
  pk.y = (unsigned)f2bf(v.z) | ((unsigned)f2bf(v.w) << 16);
  *reinterpret_cast<uint2*>(out + i) = pk;
}

// ---------------- shared NT-GEMM mainloop, BK=64 (R8-proven) ----------------
// 128x128 tile, 4 waves, double-buffered 64KB LDS, counted vmcnt(8) (loads stay
// in flight across barriers). 2 blocks/CU -> cross-block overlap hides the
// barrier drain (removing it regressed: R12; single-barrier variant neutral: R14).
// XOR-swizzled LDS via pre-swizzled global source + matching XOR on ds_read
// (conflict-free, 197K cyc measured).
__device__ __forceinline__ void gemm_mainloop64(const u16* __restrict__ A,
                                                const u16* __restrict__ W, int M0, int N0,
                                                u16* lds, f32x4_t acc[4][4], int tid) {
  const int w = tid >> 6, l = tid & 63;
  const int lrow = l & 15, kg = l >> 4;
  const int wr = (w >> 1) * 64, wc = (w & 1) * 64;
  const int row0 = tid >> 3, j0 = tid & 7;
  const unsigned jsw = (unsigned)((j0 ^ (row0 & 7)) * 8);
  unsigned offA = (unsigned)((M0 + row0) * KDIM) + jsw;
  unsigned offW = (unsigned)((N0 + row0) * KDIM) + jsw;
  const u16* A1 = A + 32 * KDIM; const u16* A2 = A + 64 * KDIM; const u16* A3 = A + 96 * KDIM;
  const u16* W1 = W + 32 * KDIM; const u16* W2 = W + 64 * KDIM; const u16* W3 = W + 96 * KDIM;
  auto issue = [&](int buf) {
    u16* da = lds + buf * 8192 + w * 512;
    u16* dw = lds + 16384 + buf * 8192 + w * 512;
    GLL(A + offA, da);          GLL(A1 + offA, da + 2048);
    GLL(A2 + offA, da + 4096);  GLL(A3 + offA, da + 6144);
    GLL(W + offW, dw);          GLL(W1 + offW, dw + 2048);
    GLL(W2 + offW, dw + 4096);  GLL(W3 + offW, dw + 6144);
    offA += 64; offW += 64;
  };
  issue(0);
  const int NT = KDIM / 64;  // 24
#pragma unroll 1
  for (int kt = 0; kt < NT; ++kt) {
    const int cur = kt & 1;
    if (kt + 1 < NT) {
      issue(cur ^ 1);
      asm volatile("s_waitcnt vmcnt(8)" ::: "memory");
    } else {
      asm volatile("s_waitcnt vmcnt(0)" ::: "memory");
    }
    __builtin_amdgcn_s_barrier();
    asm volatile("" ::: "memory");
    const u16* Ab = lds + cur * 8192;
    const u16* Wb = lds + 16384 + cur * 8192;
#pragma unroll
    for (int s = 0; s < 2; ++s) {
      bf16x8_t af[4], bf_[4];
#pragma unroll
      for (int mi = 0; mi < 4; ++mi) {
        const int row = wr + mi * 16 + lrow;
        af[mi] = *reinterpret_cast<const bf16x8_t*>(Ab + row * 64 +
                                                    (((s << 2) | kg) ^ (row & 7)) * 8);
      }
#pragma unroll
      for (int ni = 0; ni < 4; ++ni) {
        const int row = wc + ni * 16 + lrow;
        bf_[ni] = *reinterpret_cast<const bf16x8_t*>(Wb + row * 64 +
                                                     (((s << 2) | kg) ^ (row & 7)) * 8);
      }
#pragma unroll
      for (int mi = 0; mi < 4; ++mi)
#pragma unroll
        for (int ni = 0; ni < 4; ++ni)
          acc[mi][ni] = MFMA16(af[mi], bf_[ni], acc[mi][ni]);
    }
    asm volatile("s_waitcnt lgkmcnt(0)" ::: "memory");
    __builtin_amdgcn_s_barrier();
    asm volatile("" ::: "memory");
  }
}

// ---------------- QKV projection + fused RoPE/RMSNorm epilogue (per-z blocks) ----------------
// Grid 1152 flattened, XCD-chunked (8 XCDs x [8m x 18nz]); A-band L2-resident.
// Epilogue: stage C bf16 swizzled into first 16KB of LDS, then
// z=0/1: in-block RoPE+RMSNorm -> qh/kh; z=2: transpose -> vt, 16B stores.
__global__ __launch_bounds__(256) void gemm_qkv_kernel(
    const u16* __restrict__ xb, const u16* __restrict__ wq, const u16* __restrict__ wk,
    const u16* __restrict__ wv, const float* __restrict__ cosp, const float* __restrict__ sinp,
    u16* __restrict__ qh, u16* __restrict__ kh, u16* __restrict__ vt) {
  __shared__ __align__(16) u16 lds[32768];
  const int tid = threadIdx.x;
  const int wgid = blockIdx.x;
  const int xcd = wgid & 7, c = wgid >> 3;      // c in [0,144)
  const int m = ((xcd & 3) << 3) + (c & 7);     // 0..31
  const int nz = ((xcd >> 2) * 18) + (c >> 3);  // 0..35
  const int z = nz / 12, n = nz % 12;
  const int M0 = m * 128, N0 = n * 128;
  const u16* W = (z == 0) ? wq : (z == 1) ? wk : wv;
  f32x4_t acc[4][4] = {};
  gemm_mainloop64(xb, W, M0, N0, lds, acc, tid);
  const int w = tid >> 6, l = tid & 63;
  const int lrow = l & 15, kg = l >> 4;
  const int wr = (w >> 1) * 64, wc = (w & 1) * 64;
  char* cs = reinterpret_cast<char*>(lds);
  if (z == 2) {
#pragma unroll
    for (int mi = 0; mi < 4; ++mi)
#pragma unroll
      for (int ni = 0; ni < 4; ++ni)
#pragma unroll
        for (int r = 0; r < 4; ++r) {
          const int t_l = wr + mi * 16 + kg * 4 + r;
          const int d = wc + ni * 16 + lrow;
          const int bofs = (d * 256 + t_l * 2) ^ ((d & 7) << 4);
          *reinterpret_cast<u16*>(cs + bofs) = f2bf(acc[mi][ni][r]);
        }
  } else {
#pragma unroll
    for (int mi = 0; mi < 4; ++mi)
#pragma unroll
      for (int ni = 0; ni < 4; ++ni)
#pragma unroll
        for (int r = 0; r < 4; ++r) {
          const int t_l = wr + mi * 16 + kg * 4 + r;
          const int d = wc + ni * 16 + lrow;
          const int bofs = (t_l * 256 + d * 2) ^ ((t_l & 7) << 4);
          *reinterpret_cast<u16*>(cs + bofs) = f2bf(acc[mi][ni][r]);
        }
  }
  __syncthreads();
  const int rr = tid >> 1, hh = tid & 1;
  const int bb = M0 >> 11;
  const int t0 = M0 & (TSEQ - 1);
  const size_t bhn = (size_t)(bb * NHEAD + n);
  if (z == 2) {
    u16* dst = vt + (bhn * HD + rr) * TSEQ + t0 + hh * 64;
    const char* base = cs + rr * 256 + hh * 128;
#pragma unroll
    for (int j = 0; j < 8; ++j) {
      uint4 v = *reinterpret_cast<const uint4*>(base + ((j ^ (rr & 7)) * 16));
      *reinterpret_cast<uint4*>(dst + j * 8) = v;
    }
  } else {
    const int t = t0 + rr;
    const float* cosb = cosp + t * 64;
    const float* sinb = sinp + t * 64;
    const char* base = cs + rr * 256;
    float ss = 0.0f;
    unsigned pk[32];
#pragma unroll
    for (int j = 0; j < 8; ++j) {
      const int jp = (j ^ (rr & 7)) * 16;
      uint4 vo = *reinterpret_cast<const uint4*>(base + hh * 128 + jp);
      uint4 vx = *reinterpret_cast<const uint4*>(base + (hh ^ 1) * 128 + jp);
      const unsigned vo32[4] = {vo.x, vo.y, vo.z, vo.w};
      const unsigned vx32[4] = {vx.x, vx.y, vx.z, vx.w};
      const float* cj = cosb + j * 8;
      const float* sj = sinb + j * 8;
#pragma unroll
      for (int q2 = 0; q2 < 4; ++q2) {
        float o0 = bfu((u16)(vo32[q2] & 0xffffu)), o1 = bfu((u16)(vo32[q2] >> 16));
        float x0 = bfu((u16)(vx32[q2] & 0xffffu)), x1 = bfu((u16)(vx32[q2] >> 16));
        float cc0 = cj[q2 * 2], cc1 = cj[q2 * 2 + 1];
        float s0 = sj[q2 * 2], s1 = sj[q2 * 2 + 1];
        float y0 = hh ? __builtin_fmaf(o0, cc0, -x0 * s0) : __builtin_fmaf(o0, cc0, x0 * s0);
        float y1 = hh ? __builtin_fmaf(o1, cc1, -x1 * s1) : __builtin_fmaf(o1, cc1, x1 * s1);
        ss = __builtin_fmaf(y0, y0, __builtin_fmaf(y1, y1, ss));
        pk[j * 4 + q2] = (unsigned)f2bf(y0) | ((unsigned)f2bf(y1) << 16);
      }
    }
    ss += __shfl_xor(ss, 1, 64);
    const float rinv = rsqrtf(ss * (1.0f / 128.0f) + EPS_F);
    u16* dst = ((z == 0) ? qh : kh) + (bhn * TSEQ + t) * HD + hh * 64;
#pragma unroll
    for (int j = 0; j < 8; ++j) {
      unsigned o[4];
#pragma unroll
      for (int q2 = 0; q2 < 4; ++q2) {
        float y0 = bfu((u16)(pk[j * 4 + q2] & 0xffffu)) * rinv;
        float y1 = bfu((u16)(pk[j * 4 + q2] >> 16)) * rinv;
        o[q2] = (unsigned)f2bf(y0) | ((unsigned)f2bf(y1) << 16);
      }
      uint4 v;
      v.x = o[0]; v.y = o[1]; v.z = o[2]; v.w = o[3];
      *reinterpret_cast<uint4*>(dst + j * 8) = v;
    }
  }
}

// ---------------- output projection (flattened grid, XCD-chunked; R8-proven) ----------------
__global__ __launch_bounds__(256) void gemm_out_kernel(const u16* __restrict__ yh,
                                                       const u16* __restrict__ wp,
                                                       float* __restrict__ out) {
  __shared__ __align__(16) u16 lds[32768];
  const int tid = threadIdx.x;
  const int wgid = blockIdx.x;
  const int xcd = wgid & 7, c = wgid >> 3;
  const int m = ((xcd & 3) << 3) + (c & 7);
  const int n = ((xcd >> 2) * 6) + (c >> 3);
  const int M0 = m * 128, N0 = n * 128;
  f32x4_t acc[4][4] = {};
  gemm_mainloop64(yh, wp, M0, N0, lds, acc, tid);
  const int w = tid >> 6, l = tid & 63;
  const int lrow = l & 15, kg = l >> 4;
  const int wr = (w >> 1) * 64, wc = (w & 1) * 64;
#pragma unroll
  for (int mi = 0; mi < 4; ++mi)
#pragma unroll
    for (int ni = 0; ni < 4; ++ni)
#pragma unroll
      for (int r = 0; r < 4; ++r) {
        const int grow = M0 + wr + mi * 16 + kg * 4 + r;
        const int gcol = N0 + wc + ni * 16 + lrow;
        out[(size_t)grow * HIDDEN + gcol] = acc[mi][ni][r];
      }
}

// ---------------- flash attention: 2-barrier pipeline, dbuf K AND V (R9-proven) ----------------
// 8 waves x 16 q-rows = 128 q-rows/block. Per iter: issueK(next) | vmcnt(2) | b1 |
// issueV(next) | QK | softmax | Pwrite+lgkm | b2 | PV. Interior tiles skip mask
// VALU (wave-uniform test); row-sum reduce deferred to one post-loop shuffle.
__global__ __launch_bounds__(512, 4) void attn_kernel(const u16* __restrict__ qh,
                                                      const u16* __restrict__ kh,
                                                      const u16* __restrict__ vt,
                                                      u16* __restrict__ yh,
                                                      const int* __restrict__ winp) {
  __shared__ __align__(16) u16 Kl[2][8192];  // [buf][64 keys x 128 d], swizzled
  __shared__ __align__(16) u16 Vl[2][8192];  // [buf][128 d x 64 t], swizzled
  __shared__ __align__(16) u16 Pl[8][1024];  // per-wave 16x64 P, swizzled
  const int tid = threadIdx.x, w = tid >> 6, l = tid & 63;
  const int lrow = l & 15, kg = l >> 4;
  const int bid = blockIdx.x;  // 384 = 8 XCDs x 48
  const int swz = (bid & 7) * 48 + (bid >> 3);
  const int qb = swz & 15;  // q-block (128 rows) within (b,h)
  const int bh = swz >> 4;  // 0..23
  const int h = bh % NHEAD, b = bh / NHEAD;
  const int win = winp[0];
  const u16* Q = qh + (size_t)bh * TSEQ * HD;
  const u16* K = kh + (size_t)bh * TSEQ * HD;
  const u16* V = vt + (size_t)bh * HD * TSEQ;
  const int qw = qb * 128 + w * 16;  // this wave's 16 q-rows
  bf16x8_t aq[4];
#pragma unroll
  for (int ks = 0; ks < 4; ++ks)
    aq[ks] = *reinterpret_cast<const bf16x8_t*>(Q + (qw + lrow) * HD + ks * 32 + kg * 8);
  float lsum[4] = {0.f, 0.f, 0.f, 0.f};  // per-lane partial row sums (reduced post-loop)
  f32x4_t accv[8] = {};
  int lo = qb * 128 - win;
  if (lo < 0) lo = 0;
  lo &= ~63;
  const int last = qb * 128 + 64;  // last KV tile start (diagonal tile)

  u16* Pw = &Pl[w][0];

  auto stage_k = [&](int kv, int buf) {
#pragma unroll
    for (int i = 0; i < 2; ++i) {
      const int c = i * 512 + w * 64 + l;
      const int row = c >> 4, j = c & 15;
      const u16* src = K + (size_t)(kv + row) * HD + ((j ^ (row & 7)) * 8);
      GLL(src, &Kl[buf][0] + i * 4096 + w * 512);
    }
  };
  auto stage_v = [&](int kv, int buf) {
#pragma unroll
    for (int i = 0; i < 2; ++i) {
      const int c = i * 512 + w * 64 + l;
      const int row = c >> 3, j = c & 7;
      const u16* src = V + (size_t)row * TSEQ + kv + ((j ^ (row & 7)) * 8);
      GLL(src, &Vl[buf][0] + i * 4096 + w * 512);
    }
  };

  stage_k(lo, 0);
  stage_v(lo, 0);  // prologue: 4 loads in flight
  int it = 0;
  for (int kv = lo; kv <= last; kv += 64, ++it) {
    const int cur = it & 1;
    const int kpre = (kv + 64 <= last) ? kv + 64 : last;  // clamp tail prefetch
    stage_k(kpre, cur ^ 1);                               // +2 -> 6 outstanding
    asm volatile("s_waitcnt vmcnt(2)" ::: "memory");      // K(kv),V(kv) landed
    __builtin_amdgcn_s_barrier();                         // b1
    asm volatile("" ::: "memory");
    stage_v(kpre, cur ^ 1);  // +2 (Vl[cur^1] PV-reads all finished before b1)
    // ---- S = Q K^T (16 x 64) from LDS ----
    const u16* Kb = &Kl[cur][0];
    f32x4_t s[4] = {};
#pragma unroll
    for (int n = 0; n < 4; ++n) {
      const int row = n * 16 + lrow;
#pragma unroll
      for (int ks = 0; ks < 4; ++ks) {
        bf16x8_t bk = *reinterpret_cast<const bf16x8_t*>(
            Kb + row * 128 + (((ks << 2) | kg) ^ (row & 7)) * 8);
        s[n] = MFMA16(aq[ks], bk, s[n]);
      }
    }
    // ---- softmax: interior tiles need no mask (wave-uniform test) ----
    float ps[4][4];
    const bool interior = (kv + 63 <= qw) && ((qw + 15) - kv <= win);
    if (interior) {
#pragma unroll
      for (int n = 0; n < 4; ++n)
#pragma unroll
        for (int r = 0; r < 4; ++r)
          ps[n][r] = exp2f(__builtin_fmaf(s[n][r], SCALE_LOG2E, -FIXSUB));
    } else {
#pragma unroll
      for (int n = 0; n < 4; ++n) {
        const int key = kv + n * 16 + lrow;
#pragma unroll
        for (int r = 0; r < 4; ++r) {
          const int rowq = qw + kg * 4 + r;
          const bool ok = (key <= rowq) && (rowq - key <= win);
          ps[n][r] = ok ? exp2f(__builtin_fmaf(s[n][r], SCALE_LOG2E, -FIXSUB)) : 0.0f;
        }
      }
    }
#pragma unroll
    for (int r = 0; r < 4; ++r)
      lsum[r] += (ps[0][r] + ps[1][r]) + (ps[2][r] + ps[3][r]);
    // ---- P (bf16) -> swizzled per-wave LDS: D-frag -> A-frag layout ----
#pragma unroll
    for (int n = 0; n < 4; ++n)
#pragma unroll
      for (int r = 0; r < 4; ++r) {
        const int rp = kg * 4 + r;
        int bofs = rp * 128 + (n * 16 + lrow) * 2;
        bofs ^= (rp & 7) << 4;
        *reinterpret_cast<u16*>(reinterpret_cast<char*>(Pw) + bofs) = f2bf(ps[n][r]);
      }
    asm volatile("s_waitcnt lgkmcnt(0)" ::: "memory");
    __builtin_amdgcn_s_barrier();  // b2: QK reads of Kl[cur] done before next issueK
    asm volatile("" ::: "memory");
    // ---- O += P V ----
    bf16x8_t ap[2];
#pragma unroll
    for (int k2 = 0; k2 < 2; ++k2) {
      int bofs = lrow * 128 + k2 * 64 + kg * 16;
      bofs ^= (lrow & 7) << 4;
      ap[k2] = *reinterpret_cast<const bf16x8_t*>(reinterpret_cast<const char*>(Pw) + bofs);
    }
    const u16* Vb = &Vl[cur][0];
#pragma unroll
    for (int k2 = 0; k2 < 2; ++k2)
#pragma unroll
      for (int dn = 0; dn < 8; ++dn) {
        const int row = dn * 16 + lrow;
        bf16x8_t bv = *reinterpret_cast<const bf16x8_t*>(
            Vb + row * 64 + (((k2 << 2) | kg) ^ (row & 7)) * 8);
        accv[dn] = MFMA16(ap[k2], bv, accv[dn]);
      }
  }
  // ---- deferred row-sum reduce (within each 16-lane lrow group) ----
#pragma unroll
  for (int off = 1; off < 16; off <<= 1)
#pragma unroll
    for (int r = 0; r < 4; ++r) lsum[r] += __shfl_xor(lsum[r], off, 64);
  float inv[4];
#pragma unroll
  for (int r = 0; r < 4; ++r) inv[r] = 1.0f / lsum[r];
#pragma unroll
  for (int dn = 0; dn < 8; ++dn)
#pragma unroll
    for (int r = 0; r < 4; ++r) {
      const int rowg = b * TSEQ + qw + kg * 4 + r;
      const int col = h * HD + dn * 16 + lrow;
      yh[(size_t)rowg * HIDDEN + col] = f2bf(accv[dn][r] * inv[r]);
    }
}

extern "C" void kernel_launch(void* const* d_in, const int* in_sizes, int n_in, void* d_out,
                              int out_size, void* d_ws, size_t ws_size, hipStream_t stream) {
  const float* x = (const float*)d_in[0];
  const float* cosp = (const float*)d_in[1];
  const float* sinp = (const float*)d_in[2];
  const float* Wq = (const float*)d_in[3];
  const float* Wk = (const float*)d_in[4];
  const float* Wv = (const float*)d_in[5];
  const float* Wp = (const float*)d_in[6];
  const int* winp = (const int*)d_in[7];

  char* ws = (char*)d_ws;
  size_t off = 0;
  auto alloc = [&](size_t bytes) {
    char* p = ws + off;
    off += (bytes + 255) & ~(size_t)255;
    return p;
  };
  u16* xb = (u16*)alloc((size_t)NROWS * HIDDEN * 2);
  u16* wqb = (u16*)alloc((size_t)HIDDEN * HIDDEN * 2);
  u16* wkb = (u16*)alloc((size_t)HIDDEN * HIDDEN * 2);
  u16* wvb = (u16*)alloc((size_t)HIDDEN * HIDDEN * 2);
  u16* wpb = (u16*)alloc((size_t)HIDDEN * HIDDEN * 2);
  u16* qh = (u16*)alloc((size_t)NROWS * HIDDEN * 2);
  u16* kh = (u16*)alloc((size_t)NROWS * HIDDEN * 2);
  u16* vt = (u16*)alloc((size_t)NROWS * HIDDEN * 2);
  u16* yh = (u16*)alloc((size_t)NROWS * HIDDEN * 2);

  const int nx = NROWS * HIDDEN;   // 6291456
  const int nw = HIDDEN * HIDDEN;  // 2359296
  cast_kernel<<<nx / 1024, 256, 0, stream>>>(x, xb, nx);
  cast4_kernel<<<dim3(nw / 1024, 4), 256, 0, stream>>>(Wq, Wk, Wv, Wp, wqb, wkb, wvb, wpb, nw);

  gemm_qkv_kernel<<<dim3(1152), 256, 0, stream>>>(xb, wqb, wkb, wvb, cosp, sinp, qh, kh, vt);
  attn_kernel<<<dim3(384), 512, 0, stream>>>(qh, kh, vt, yh, winp);
  gemm_out_kernel<<<dim3(384), 256, 0, stream>>>(yh, wpb, (float*)d_out);
}

// Round 16
// 184.794 us; speedup vs baseline: 1.0223x; 1.0061x over previous
//
#include <hip/hip_runtime.h>
#include <stdint.h>

#define HIDDEN 1536
#define NHEAD 12
#define HD 128
#define TSEQ 2048
#define NROWS 4096
#define KDIM HIDDEN
#define EPS_F 1.1920928955078125e-07f
// (1/sqrt(128)) * log2(e)
#define SCALE_LOG2E 0.12751879110195655f
// fixed softmax shift (log2 domain): scores bounded by sqrt(128)=11.314 (RMS-normed
// q,k => |q||k|<=128 by Cauchy-Schwarz), *log2(e) = 16.32; use 16.6 for bf16 margin.
#define FIXSUB 16.6f

typedef unsigned short u16;
typedef __bf16 bf16x8_t __attribute__((ext_vector_type(8)));
typedef float f32x4_t __attribute__((ext_vector_type(4)));

#define MFMA16(a, b, c) __builtin_amdgcn_mfma_f32_16x16x32_bf16((a), (b), (c), 0, 0, 0)
#define GLL(srcp, dstp) \
  __builtin_amdgcn_global_load_lds((const __attribute__((address_space(1))) void*)(srcp), \
                                   (__attribute__((address_space(3))) void*)(dstp), 16, 0, 0)

__device__ __forceinline__ u16 f2bf(float f) {
  unsigned u = __builtin_bit_cast(unsigned, f);
  u = (u + 0x7fffu + ((u >> 16) & 1u)) >> 16;
  return (u16)u;
}
__device__ __forceinline__ float bfu(u16 v) {
  return __builtin_bit_cast(float, ((unsigned)v) << 16);
}

// ---------------- cast fp32 -> bf16 (vectorized) ----------------
__global__ __launch_bounds__(256) void cast_kernel(const float* __restrict__ in,
                                                   u16* __restrict__ out, int n) {
  int i = (blockIdx.x * 256 + threadIdx.x) * 4;
  if (i >= n) return;
  float4 v = *reinterpret_cast<const float4*>(in + i);
  uint2 pk;
  pk.x = (unsigned)f2bf(v.x) | ((unsigned)f2bf(v.y) << 16);
  pk.y = (unsigned)f2bf(v.z) | ((unsigned)f2bf(v.w) << 16);
  *reinterpret_cast<uint2*>(out + i) = pk;
}

// 4 equal-size weight casts in one launch (blockIdx.y selects)
__global__ __launch_bounds__(256) void cast4_kernel(
    const float* __restrict__ a, const float* __restrict__ b, const float* __restrict__ c,
    const float* __restrict__ d, u16* __restrict__ oa, u16* __restrict__ ob,
    u16* __restrict__ oc, u16* __restrict__ od, int n) {
  const float* in;
  u16* out;
  switch (blockIdx.y) {
    case 0: in = a; out = oa; break;
    case 1: in = b; out = ob; break;
    case 2: in = c; out = oc; break;
    default: in = d; out = od; break;
  }
  int i = (blockIdx.x * 256 + threadIdx.x) * 4;
  if (i >= n) return;
  float4 v = *reinterpret_cast<const float4*>(in + i);
  uint2 pk;
  pk.x = (unsigned)f2bf(v.x) | ((unsigned)f2bf(v.y) << 16);
  pk.y = (unsigned)f2bf(v.z) | ((unsigned)f2bf(v.w) << 16);
  *reinterpret_cast<uint2*>(out + i) = pk;
}

// ---------------- shared NT-GEMM mainloop, BK=64, 8 waves (512 thr) ----------------
// 128x128 tile re-partitioned over 8 waves (2M x 4N, 64x32 out/wave): same LDS
// (64KB -> 2 blocks/CU) but 16 waves/CU = 4 waves/SIMD (2x TLP vs R13) to hide
// the barrier drain via cross-wave overlap (m114). Topology identical to R8/R13:
// issue-next | counted vmcnt(4) | barrier | ds_read+MFMA | lgkm | barrier.
// XOR-swizzled LDS via pre-swizzled global source + matching XOR on ds_read.
// LDS (u16): A bufs [0,8192),[8192,16384); W bufs [16384,24576),[24576,32768).
__device__ __forceinline__ void gemm_mainloop64(const u16* __restrict__ A,
                                                const u16* __restrict__ W, int M0, int N0,
                                                u16* lds, f32x4_t acc[4][2], int tid) {
  const int w = tid >> 6, l = tid & 63;
  const int lrow = l & 15, kg = l >> 4;
  const int wm = w >> 2, wn = w & 3;  // 2 M-waves x 4 N-waves
  const int rbase = wm * 64, cbase = wn * 32;
  // staging: 1024 chunks/matrix; thread covers chunks tid and tid+512 (rows +64,
  // 64 % 8 == 0 -> swizzle term pass-invariant). 4 GLL/thread/tile.
  const int row0 = tid >> 3, j0 = tid & 7;
  const unsigned jsw = (unsigned)((j0 ^ (row0 & 7)) * 8);
  unsigned offA = (unsigned)((M0 + row0) * KDIM) + jsw;
  unsigned offW = (unsigned)((N0 + row0) * KDIM) + jsw;
  const size_t R64 = (size_t)64 * KDIM;
  auto issue = [&](int buf) {
    u16* da = lds + buf * 8192 + w * 512;
    u16* dw = lds + 16384 + buf * 8192 + w * 512;
    GLL(A + offA, da);
    GLL(A + offA + R64, da + 4096);
    GLL(W + offW, dw);
    GLL(W + offW + R64, dw + 4096);
    offA += 64;
    offW += 64;
  };
  issue(0);
  const int NT = KDIM / 64;  // 24
#pragma unroll 1
  for (int kt = 0; kt < NT; ++kt) {
    const int cur = kt & 1;
    if (kt + 1 < NT) {
      issue(cur ^ 1);
      asm volatile("s_waitcnt vmcnt(4)" ::: "memory");  // current buffer's 4 loads done
    } else {
      asm volatile("s_waitcnt vmcnt(0)" ::: "memory");
    }
    __builtin_amdgcn_s_barrier();
    asm volatile("" ::: "memory");
    const u16* Ab = lds + cur * 8192;
    const u16* Wb = lds + 16384 + cur * 8192;
#pragma unroll
    for (int s = 0; s < 2; ++s) {  // two K=32 sub-steps
      bf16x8_t af[4], bf_[2];
#pragma unroll
      for (int mi = 0; mi < 4; ++mi) {
        const int row = rbase + mi * 16 + lrow;
        af[mi] = *reinterpret_cast<const bf16x8_t*>(Ab + row * 64 +
                                                    (((s << 2) | kg) ^ (row & 7)) * 8);
      }
#pragma unroll
      for (int ni = 0; ni < 2; ++ni) {
        const int row = cbase + ni * 16 + lrow;
        bf_[ni] = *reinterpret_cast<const bf16x8_t*>(Wb + row * 64 +
                                                     (((s << 2) | kg) ^ (row & 7)) * 8);
      }
#pragma unroll
      for (int mi = 0; mi < 4; ++mi)
#pragma unroll
        for (int ni = 0; ni < 2; ++ni)
          acc[mi][ni] = MFMA16(af[mi], bf_[ni], acc[mi][ni]);
    }
    asm volatile("s_waitcnt lgkmcnt(0)" ::: "memory");
    __builtin_amdgcn_s_barrier();
    asm volatile("" ::: "memory");
  }
}

// ---------------- QKV projection + fused RoPE/RMSNorm epilogue (per-z blocks) ----------------
// Grid 1152 flattened, XCD-chunked (8 XCDs x [8m x 18nz]); A-band L2-resident.
// Epilogue: stage C bf16 swizzled into first 32KB of LDS, then (512 threads)
// z=0/1: in-block RoPE+RMSNorm -> qh/kh (4 threads/row); z=2: transpose -> vt.
__global__ __launch_bounds__(512, 4) void gemm_qkv_kernel(
    const u16* __restrict__ xb, const u16* __restrict__ wq, const u16* __restrict__ wk,
    const u16* __restrict__ wv, const float* __restrict__ cosp, const float* __restrict__ sinp,
    u16* __restrict__ qh, u16* __restrict__ kh, u16* __restrict__ vt) {
  __shared__ __align__(16) u16 lds[32768];
  const int tid = threadIdx.x;
  const int wgid = blockIdx.x;
  const int xcd = wgid & 7, c = wgid >> 3;      // c in [0,144)
  const int m = ((xcd & 3) << 3) + (c & 7);     // 0..31
  const int nz = ((xcd >> 2) * 18) + (c >> 3);  // 0..35
  const int z = nz / 12, n = nz % 12;
  const int M0 = m * 128, N0 = n * 128;
  const u16* W = (z == 0) ? wq : (z == 1) ? wk : wv;
  f32x4_t acc[4][2] = {};
  gemm_mainloop64(xb, W, M0, N0, lds, acc, tid);
  const int w = tid >> 6, l = tid & 63;
  const int lrow = l & 15, kg = l >> 4;
  const int wm = w >> 2, wn = w & 3;
  char* cs = reinterpret_cast<char*>(lds);
  // ---- stage C tile as bf16 (mainloop's final barrier makes this safe) ----
  if (z == 2) {
    // [d(128)][t(128)] rows of 256B, XOR (d&7) on 16B-chunk index
#pragma unroll
    for (int mi = 0; mi < 4; ++mi)
#pragma unroll
      for (int ni = 0; ni < 2; ++ni)
#pragma unroll
        for (int r = 0; r < 4; ++r) {
          const int t_l = wm * 64 + mi * 16 + kg * 4 + r;
          const int d = wn * 32 + ni * 16 + lrow;
          const int bofs = (d * 256 + t_l * 2) ^ ((d & 7) << 4);
          *reinterpret_cast<u16*>(cs + bofs) = f2bf(acc[mi][ni][r]);
        }
  } else {
    // [t(128)][d(128)] rows of 256B, XOR (t&7) on 16B-chunk index
#pragma unroll
    for (int mi = 0; mi < 4; ++mi)
#pragma unroll
      for (int ni = 0; ni < 2; ++ni)
#pragma unroll
        for (int r = 0; r < 4; ++r) {
          const int t_l = wm * 64 + mi * 16 + kg * 4 + r;
          const int d = wn * 32 + ni * 16 + lrow;
          const int bofs = (t_l * 256 + d * 2) ^ ((t_l & 7) << 4);
          *reinterpret_cast<u16*>(cs + bofs) = f2bf(acc[mi][ni][r]);
        }
  }
  __syncthreads();
  const int bb = M0 >> 11;  // batch (tile never straddles)
  const int t0 = M0 & (TSEQ - 1);
  const size_t bhn = (size_t)(bb * NHEAD + n);
  if (z == 2) {
    // coalesced [d][t] store: 128 d x 4 t-quarters (32 t each)
    const int dd = tid >> 2, tq = tid & 3;
    u16* dst = vt + (bhn * HD + dd) * TSEQ + t0 + tq * 32;
    const char* rb = cs + dd * 256;
#pragma unroll
    for (int j = 0; j < 4; ++j) {
      const int jj = tq * 4 + j;
      uint4 v = *reinterpret_cast<const uint4*>(rb + ((jj ^ (dd & 7)) * 16));
      *reinterpret_cast<uint4*>(dst + j * 8) = v;
    }
  } else {
    // RoPE + RMSNorm: 4 threads per token row; thread owns d in [qd*32, qd*32+32)
    const int rr = tid >> 2, qd = tid & 3;
    const int hh = qd >> 1;  // 0: d<64 (y=o*c+x*s), 1: d>=64 (y=o*c-x*s)
    const int t = t0 + rr;
    const float* cosb = cosp + t * 64 + (qd & 1) * 32;  // cos index = d & 63
    const float* sinb = sinp + t * 64 + (qd & 1) * 32;
    const char* base = cs + rr * 256;
    float ss = 0.0f;
    unsigned pk[16];  // 32 rope'd values packed bf16x2
#pragma unroll
    for (int j = 0; j < 4; ++j) {
      const int jo = qd * 4 + j;        // own chunk (8 d)
      const int jx = (qd ^ 2) * 4 + j;  // partner chunk (d ^ 64)
      uint4 vo = *reinterpret_cast<const uint4*>(base + ((jo ^ (rr & 7)) * 16));
      uint4 vx = *reinterpret_cast<const uint4*>(base + ((jx ^ (rr & 7)) * 16));
      const unsigned vo32[4] = {vo.x, vo.y, vo.z, vo.w};
      const unsigned vx32[4] = {vx.x, vx.y, vx.z, vx.w};
      const float* cj = cosb + j * 8;
      const float* sj = sinb + j * 8;
#pragma unroll
      for (int q2 = 0; q2 < 4; ++q2) {
        float o0 = bfu((u16)(vo32[q2] & 0xffffu)), o1 = bfu((u16)(vo32[q2] >> 16));
        float x0 = bfu((u16)(vx32[q2] & 0xffffu)), x1 = bfu((u16)(vx32[q2] >> 16));
        float cc0 = cj[q2 * 2], cc1 = cj[q2 * 2 + 1];
        float s0 = sj[q2 * 2], s1 = sj[q2 * 2 + 1];
        float y0 = hh ? __builtin_fmaf(o0, cc0, -x0 * s0) : __builtin_fmaf(o0, cc0, x0 * s0);
        float y1 = hh ? __builtin_fmaf(o1, cc1, -x1 * s1) : __builtin_fmaf(o1, cc1, x1 * s1);
        ss = __builtin_fmaf(y0, y0, __builtin_fmaf(y1, y1, ss));
        pk[j * 4 + q2] = (unsigned)f2bf(y0) | ((unsigned)f2bf(y1) << 16);
      }
    }
    // row sum over the 4 consecutive lanes of this token row
    ss += __shfl_xor(ss, 1, 64);
    ss += __shfl_xor(ss, 2, 64);
    const float rinv = rsqrtf(ss * (1.0f / 128.0f) + EPS_F);
    u16* dst = ((z == 0) ? qh : kh) + (bhn * TSEQ + t) * HD + qd * 32;
#pragma unroll
    for (int j = 0; j < 4; ++j) {
      unsigned o[4];
#pragma unroll
      for (int q2 = 0; q2 < 4; ++q2) {
        float y0 = bfu((u16)(pk[j * 4 + q2] & 0xffffu)) * rinv;
        float y1 = bfu((u16)(pk[j * 4 + q2] >> 16)) * rinv;
        o[q2] = (unsigned)f2bf(y0) | ((unsigned)f2bf(y1) << 16);
      }
      uint4 v;
      v.x = o[0]; v.y = o[1]; v.z = o[2]; v.w = o[3];
      *reinterpret_cast<uint4*>(dst + j * 8) = v;
    }
  }
}

// ---------------- output projection (flattened grid, XCD-chunked; 512 thr) ----------------
__global__ __launch_bounds__(512, 4) void gemm_out_kernel(const u16* __restrict__ yh,
                                                          const u16* __restrict__ wp,
                                                          float* __restrict__ out) {
  __shared__ __align__(16) u16 lds[32768];
  const int tid = threadIdx.x;
  const int wgid = blockIdx.x;
  const int xcd = wgid & 7, c = wgid >> 3;
  const int m = ((xcd & 3) << 3) + (c & 7);
  const int n = ((xcd >> 2) * 6) + (c >> 3);
  const int M0 = m * 128, N0 = n * 128;
  f32x4_t acc[4][2] = {};
  gemm_mainloop64(yh, wp, M0, N0, lds, acc, tid);
  const int w = tid >> 6, l = tid & 63;
  const int lrow = l & 15, kg = l >> 4;
  const int wm = w >> 2, wn = w & 3;
#pragma unroll
  for (int mi = 0; mi < 4; ++mi)
#pragma unroll
    for (int ni = 0; ni < 2; ++ni)
#pragma unroll
      for (int r = 0; r < 4; ++r) {
        const int grow = M0 + wm * 64 + mi * 16 + kg * 4 + r;
        const int gcol = N0 + wn * 32 + ni * 16 + lrow;
        out[(size_t)grow * HIDDEN + gcol] = acc[mi][ni][r];
      }
}

// ---------------- flash attention: 2-barrier pipeline, dbuf K AND V (R9-proven) ----------------
__global__ __launch_bounds__(512, 4) void attn_kernel(const u16* __restrict__ qh,
                                                      const u16* __restrict__ kh,
                                                      const u16* __restrict__ vt,
                                                      u16* __restrict__ yh,
                                                      const int* __restrict__ winp) {
  __shared__ __align__(16) u16 Kl[2][8192];  // [buf][64 keys x 128 d], swizzled
  __shared__ __align__(16) u16 Vl[2][8192];  // [buf][128 d x 64 t], swizzled
  __shared__ __align__(16) u16 Pl[8][1024];  // per-wave 16x64 P, swizzled
  const int tid = threadIdx.x, w = tid >> 6, l = tid & 63;
  const int lrow = l & 15, kg = l >> 4;
  const int bid = blockIdx.x;  // 384 = 8 XCDs x 48
  const int swz = (bid & 7) * 48 + (bid >> 3);
  const int qb = swz & 15;  // q-block (128 rows) within (b,h)
  const int bh = swz >> 4;  // 0..23
  const int h = bh % NHEAD, b = bh / NHEAD;
  const int win = winp[0];
  const u16* Q = qh + (size_t)bh * TSEQ * HD;
  const u16* K = kh + (size_t)bh * TSEQ * HD;
  const u16* V = vt + (size_t)bh * HD * TSEQ;
  const int qw = qb * 128 + w * 16;  // this wave's 16 q-rows
  bf16x8_t aq[4];
#pragma unroll
  for (int ks = 0; ks < 4; ++ks)
    aq[ks] = *reinterpret_cast<const bf16x8_t*>(Q + (qw + lrow) * HD + ks * 32 + kg * 8);
  float lsum[4] = {0.f, 0.f, 0.f, 0.f};  // per-lane partial row sums (reduced post-loop)
  f32x4_t accv[8] = {};
  int lo = qb * 128 - win;
  if (lo < 0) lo = 0;
  lo &= ~63;
  const int last = qb * 128 + 64;  // last KV tile start (diagonal tile)

  u16* Pw = &Pl[w][0];

  auto stage_k = [&](int kv, int buf) {
#pragma unroll
    for (int i = 0; i < 2; ++i) {
      const int c = i * 512 + w * 64 + l;
      const int row = c >> 4, j = c & 15;
      const u16* src = K + (size_t)(kv + row) * HD + ((j ^ (row & 7)) * 8);
      GLL(src, &Kl[buf][0] + i * 4096 + w * 512);
    }
  };
  auto stage_v = [&](int kv, int buf) {
#pragma unroll
    for (int i = 0; i < 2; ++i) {
      const int c = i * 512 + w * 64 + l;
      const int row = c >> 3, j = c & 7;
      const u16* src = V + (size_t)row * TSEQ + kv + ((j ^ (row & 7)) * 8);
      GLL(src, &Vl[buf][0] + i * 4096 + w * 512);
    }
  };

  stage_k(lo, 0);
  stage_v(lo, 0);  // prologue: 4 loads in flight
  int it = 0;
  for (int kv = lo; kv <= last; kv += 64, ++it) {
    const int cur = it & 1;
    const int kpre = (kv + 64 <= last) ? kv + 64 : last;  // clamp tail prefetch
    stage_k(kpre, cur ^ 1);                               // +2 -> 6 outstanding
    asm volatile("s_waitcnt vmcnt(2)" ::: "memory");      // K(kv),V(kv) landed
    __builtin_amdgcn_s_barrier();                         // b1
    asm volatile("" ::: "memory");
    stage_v(kpre, cur ^ 1);  // +2 (Vl[cur^1] PV-reads all finished before b1)
    // ---- S = Q K^T (16 x 64) from LDS ----
    const u16* Kb = &Kl[cur][0];
    f32x4_t s[4] = {};
#pragma unroll
    for (int n = 0; n < 4; ++n) {
      const int row = n * 16 + lrow;
#pragma unroll
      for (int ks = 0; ks < 4; ++ks) {
        bf16x8_t bk = *reinterpret_cast<const bf16x8_t*>(
            Kb + row * 128 + (((ks << 2) | kg) ^ (row & 7)) * 8);
        s[n] = MFMA16(aq[ks], bk, s[n]);
      }
    }
    // ---- softmax: interior tiles need no mask (wave-uniform test) ----
    float ps[4][4];
    const bool interior = (kv + 63 <= qw) && ((qw + 15) - kv <= win);
    if (interior) {
#pragma unroll
      for (int n = 0; n < 4; ++n)
#pragma unroll
        for (int r = 0; r < 4; ++r)
          ps[n][r] = exp2f(__builtin_fmaf(s[n][r], SCALE_LOG2E, -FIXSUB));
    } else {
#pragma unroll
      for (int n = 0; n < 4; ++n) {
        const int key = kv + n * 16 + lrow;
#pragma unroll
        for (int r = 0; r < 4; ++r) {
          const int rowq = qw + kg * 4 + r;
          const bool ok = (key <= rowq) && (rowq - key <= win);
          ps[n][r] = ok ? exp2f(__builtin_fmaf(s[n][r], SCALE_LOG2E, -FIXSUB)) : 0.0f;
        }
      }
    }
#pragma unroll
    for (int r = 0; r < 4; ++r)
      lsum[r] += (ps[0][r] + ps[1][r]) + (ps[2][r] + ps[3][r]);
    // ---- P (bf16) -> swizzled per-wave LDS: D-frag -> A-frag layout ----
#pragma unroll
    for (int n = 0; n < 4; ++n)
#pragma unroll
      for (int r = 0; r < 4; ++r) {
        const int rp = kg * 4 + r;
        int bofs = rp * 128 + (n * 16 + lrow) * 2;
        bofs ^= (rp & 7) << 4;
        *reinterpret_cast<u16*>(reinterpret_cast<char*>(Pw) + bofs) = f2bf(ps[n][r]);
      }
    asm volatile("s_waitcnt lgkmcnt(0)" ::: "memory");
    __builtin_amdgcn_s_barrier();  // b2: QK reads of Kl[cur] done before next issueK
    asm volatile("" ::: "memory");
    // ---- O += P V ----
    bf16x8_t ap[2];
#pragma unroll
    for (int k2 = 0; k2 < 2; ++k2) {
      int bofs = lrow * 128 + k2 * 64 + kg * 16;
      bofs ^= (lrow & 7) << 4;
      ap[k2] = *reinterpret_cast<const bf16x8_t*>(reinterpret_cast<const char*>(Pw) + bofs);
    }
    const u16* Vb = &Vl[cur][0];
#pragma unroll
    for (int k2 = 0; k2 < 2; ++k2)
#pragma unroll
      for (int dn = 0; dn < 8; ++dn) {
        const int row = dn * 16 + lrow;
        bf16x8_t bv = *reinterpret_cast<const bf16x8_t*>(
            Vb + row * 64 + (((k2 << 2) | kg) ^ (row & 7)) * 8);
        accv[dn] = MFMA16(ap[k2], bv, accv[dn]);
      }
  }
  // ---- deferred row-sum reduce (within each 16-lane lrow group) ----
#pragma unroll
  for (int off = 1; off < 16; off <<= 1)
#pragma unroll
    for (int r = 0; r < 4; ++r) lsum[r] += __shfl_xor(lsum[r], off, 64);
  float inv[4];
#pragma unroll
  for (int r = 0; r < 4; ++r) inv[r] = 1.0f / lsum[r];
#pragma unroll
  for (int dn = 0; dn < 8; ++dn)
#pragma unroll
    for (int r = 0; r < 4; ++r) {
      const int rowg = b * TSEQ + qw + kg * 4 + r;
      const int col = h * HD + dn * 16 + lrow;
      yh[(size_t)rowg * HIDDEN + col] = f2bf(accv[dn][r] * inv[r]);
    }
}

extern "C" void kernel_launch(void* const* d_in, const int* in_sizes, int n_in, void* d_out,
                              int out_size, void* d_ws, size_t ws_size, hipStream_t stream) {
  const float* x = (const float*)d_in[0];
  const float* cosp = (const float*)d_in[1];
  const float* sinp = (const float*)d_in[2];
  const float* Wq = (const float*)d_in[3];
  const float* Wk = (const float*)d_in[4];
  const float* Wv = (const float*)d_in[5];
  const float* Wp = (const float*)d_in[6];
  const int* winp = (const int*)d_in[7];

  char* ws = (char*)d_ws;
  size_t off = 0;
  auto alloc = [&](size_t bytes) {
    char* p = ws + off;
    off += (bytes + 255) & ~(size_t)255;
    return p;
  };
  u16* xb = (u16*)alloc((size_t)NROWS * HIDDEN * 2);
  u16* wqb = (u16*)alloc((size_t)HIDDEN * HIDDEN * 2);
  u16* wkb = (u16*)alloc((size_t)HIDDEN * HIDDEN * 2);
  u16* wvb = (u16*)alloc((size_t)HIDDEN * HIDDEN * 2);
  u16* wpb = (u16*)alloc((size_t)HIDDEN * HIDDEN * 2);
  u16* qh = (u16*)alloc((size_t)NROWS * HIDDEN * 2);
  u16* kh = (u16*)alloc((size_t)NROWS * HIDDEN * 2);
  u16* vt = (u16*)alloc((size_t)NROWS * HIDDEN * 2);
  u16* yh = (u16*)alloc((size_t)NROWS * HIDDEN * 2);

  const int nx = NROWS * HIDDEN;   // 6291456
  const int nw = HIDDEN * HIDDEN;  // 2359296
  cast_kernel<<<nx / 1024, 256, 0, stream>>>(x, xb, nx);
  cast4_kernel<<<dim3(nw / 1024, 4), 256, 0, stream>>>(Wq, Wk, Wv, Wp, wqb, wkb, wvb, wpb, nw);

  gemm_qkv_kernel<<<dim3(1152), 512, 0, stream>>>(xb, wqb, wkb, wvb, cosp, sinp, qh, kh, vt);
  attn_kernel<<<dim3(384), 512, 0, stream>>>(qh, kh, vt, yh, winp);
  gemm_out_kernel<<<dim3(384), 512, 0, stream>>>(yh, wpb, (float*)d_out);
}